// Round 6
// baseline (376.599 us; speedup 1.0000x reference)
//
#include <hip/hip_runtime.h>
#include <math.h>

#define BB 32
#define NN 2048
#define D_IN 320
#define H1 160
#define H2 80
#define H4 5

typedef __attribute__((ext_vector_type(8))) short short8;
typedef __attribute__((ext_vector_type(4))) short short4v;
typedef __attribute__((ext_vector_type(4))) float f32x4;

__device__ inline ushort f2bf(float f) {
    union { float f; unsigned u; } v; v.f = f;
    unsigned r = v.u + 0x7fff + ((v.u >> 16) & 1);   // RNE
    return (ushort)(r >> 16);
}
__device__ inline float bf2f(ushort u) {
    union { float f; unsigned u; } v; v.u = ((unsigned)u) << 16;
    return v.f;
}
// pack 2 floats -> 2 bf16 in one dword: round-half-up add + v_perm_b32
__device__ inline unsigned pkbf(float hi, float lo) {
    union { float f; unsigned u; } a, b; a.f = hi; b.f = lo;
    return __builtin_amdgcn_perm(a.u + 0x8000u, b.u + 0x8000u, 0x07060302u);
}
union U2S { unsigned u[2]; short4v s; };

// ---------------------------------------------------------------------------
// Prep: bf16-transpose all weights (+ zero-padded graph-conv weights/biases).
//   Wt1[160][320], Wt2[80][160], Wg1T[48][96], bg1P[48], Wg2T[16][64], bg2P[16]
// ---------------------------------------------------------------------------
__global__ __launch_bounds__(256) void prep_weights_kernel(
    const float* __restrict__ W1, const float* __restrict__ W2,
    const float* __restrict__ Wg1, const float* __restrict__ bg1,
    const float* __restrict__ Wg2, const float* __restrict__ bg2,
    ushort* __restrict__ Wt1, ushort* __restrict__ Wt2,
    ushort* __restrict__ Wg1T, float* __restrict__ bg1P,
    ushort* __restrict__ Wg2T, float* __restrict__ bg2P)
{
    const int id0 = blockIdx.x * 256 + threadIdx.x;
    const int stride = gridDim.x * 256;
    for (int i = id0; i < H1 * D_IN; i += stride) {
        const int j = i / D_IN, c = i % D_IN;
        Wt1[i] = f2bf(W1[c * H1 + j]);
    }
    for (int i = id0; i < H2 * H1; i += stride) {
        const int j = i / H1, c = i % H1;
        Wt2[i] = f2bf(W2[c * H2 + j]);
    }
    for (int i = id0; i < 48 * 96; i += stride) {
        const int j = i / 96, c = i % 96;
        Wg1T[i] = (j < 40 && c < 80) ? f2bf(Wg1[c * 40 + j]) : (ushort)0;
    }
    for (int i = id0; i < 16 * 64; i += stride) {
        const int j = i / 64, c = i % 64;
        Wg2T[i] = (j < 5 && c < 40) ? f2bf(Wg2[c * 5 + j]) : (ushort)0;
    }
    if (id0 < 48) bg1P[id0] = (id0 < 40) ? bg1[id0] : 0.f;
    if (id0 < 16) bg2P[id0] = (id0 < 5) ? bg2[id0] : 0.f;
}

// ---------------------------------------------------------------------------
// MFMA MLP: h2 = relu(relu(x@W1+b1)@W2+b2). Weights read straight from
// global (L1/L2-hot); only the x-tile + h1-tile live in LDS (~22 KB).
// ---------------------------------------------------------------------------
__global__ __launch_bounds__(256, 4) void mlp_mfma_kernel(
    const float* __restrict__ x,
    const ushort* __restrict__ Wt1, const float* __restrict__ b1,
    const ushort* __restrict__ Wt2, const float* __restrict__ b2,
    ushort* __restrict__ h2, ushort* __restrict__ h2T, float* __restrict__ sq2)
{
    constexpr int XST  = 72;    // x-tile stride (bf16); 144 B = 9*16 -> b128 ok
    constexpr int H1ST = 168;   // h1-tile stride; 336 B = 21*16 -> b128 ok

    __shared__ __attribute__((aligned(16))) ushort h1t[64 * H1ST];  // aliases xs/Tbuf
    __shared__ float b1s[H1];
    __shared__ float b2s[H2];

    ushort* xs = h1t;

    const int t = threadIdx.x;
    const int lane = t & 63, w = t >> 6;
    const int colid = lane & 15, quad = lane >> 4;
    const int row0 = blockIdx.x * 64;
    const int b = row0 / NN, n0 = row0 % NN;

    if (t < H1) b1s[t] = b1[t];
    if (t < H2) b2s[t] = b2[t];

    f32x4 c1[10];
    #pragma unroll
    for (int ns = 0; ns < 10; ++ns) c1[ns] = (f32x4){0.f, 0.f, 0.f, 0.f};

    float4 xr[4];
    #pragma unroll
    for (int i = 0; i < 4; ++i) {
        const int id = t + i * 256, row = id >> 4, c4 = id & 15;
        xr[i] = *(const float4*)&x[(size_t)(row0 + row) * D_IN + c4 * 4];
    }

    for (int kc = 0; kc < 5; ++kc) {
        if (kc) __syncthreads();
        #pragma unroll
        for (int i = 0; i < 4; ++i) {
            const int id = t + i * 256, row = id >> 4, c4 = id & 15;
            uint2 up;
            up.x = pkbf(xr[i].y, xr[i].x);
            up.y = pkbf(xr[i].w, xr[i].z);
            *(uint2*)&xs[row * XST + c4 * 4] = up;
        }
        if (kc < 4) {
            const int k0 = (kc + 1) * 64;
            #pragma unroll
            for (int i = 0; i < 4; ++i) {
                const int id = t + i * 256, row = id >> 4, c4 = id & 15;
                xr[i] = *(const float4*)&x[(size_t)(row0 + row) * D_IN + k0 + c4 * 4];
            }
        }
        __syncthreads();

        short8 af[2];
        #pragma unroll
        for (int kf = 0; kf < 2; ++kf)
            af[kf] = *(const short8*)&xs[(w * 16 + colid) * XST + kf * 32 + quad * 8];
        const ushort* w1p = Wt1 + kc * 64;
        #pragma unroll
        for (int ns = 0; ns < 10; ++ns) {
            #pragma unroll
            for (int kf = 0; kf < 2; ++kf) {
                const short8 wb = *(const short8*)&w1p[(ns * 16 + colid) * D_IN + kf * 32 + quad * 8];
                c1[ns] = __builtin_amdgcn_mfma_f32_16x16x32_bf16(af[kf], wb, c1[ns], 0, 0, 0);
            }
        }
    }
    __syncthreads();                            // xs dead -> h1t reuse

    #pragma unroll
    for (int ns = 0; ns < 10; ++ns) {
        const float bj = b1s[ns * 16 + colid];
        #pragma unroll
        for (int r = 0; r < 4; ++r)
            h1t[(w * 16 + quad * 4 + r) * H1ST + ns * 16 + colid] =
                f2bf(fmaxf(c1[ns][r] + bj, 0.f));
    }
    __asm__ volatile("s_waitcnt lgkmcnt(0)" ::: "memory");  // wave-private rows

    short8 a2[5];
    #pragma unroll
    for (int kf = 0; kf < 5; ++kf)
        a2[kf] = *(const short8*)&h1t[(w * 16 + colid) * H1ST + kf * 32 + quad * 8];

    f32x4 c2[5];
    #pragma unroll
    for (int js = 0; js < 5; ++js) {
        f32x4 acc = (f32x4){0.f, 0.f, 0.f, 0.f};
        #pragma unroll
        for (int kf = 0; kf < 5; ++kf) {
            const short8 wb = *(const short8*)&Wt2[(js * 16 + colid) * H1 + kf * 32 + quad * 8];
            acc = __builtin_amdgcn_mfma_f32_16x16x32_bf16(a2[kf], wb, acc, 0, 0, 0);
        }
        c2[js] = acc;
    }
    __syncthreads();                            // h1t dead -> Tbuf reuse

    ushort* Tbuf = h1t;                         // [96][72]
    float rsq[4] = {0.f, 0.f, 0.f, 0.f};
    #pragma unroll
    for (int js = 0; js < 5; ++js) {
        const float bj = b2s[js * 16 + colid];
        #pragma unroll
        for (int r = 0; r < 4; ++r) {
            const ushort u = f2bf(fmaxf(c2[js][r] + bj, 0.f));
            const float vv = bf2f(u);
            rsq[r] += vv * vv;
            h2[(size_t)(row0 + w * 16 + quad * 4 + r) * 96 + js * 16 + colid] = u;
            Tbuf[(js * 16 + colid) * 72 + w * 16 + quad * 4 + r] = u;
        }
    }
    {
        const short8 z8 = {0, 0, 0, 0, 0, 0, 0, 0};
        if (t < 128) {
            const int row = t >> 1, part = t & 1;
            *(short8*)&h2[(size_t)(row0 + row) * 96 + 80 + part * 8] = z8;
        }
        if (t < 128) {
            const int row = 80 + (t >> 3), part = t & 7;
            *(short8*)&Tbuf[row * 72 + part * 8] = z8;
        }
    }
    #pragma unroll
    for (int m = 1; m <= 8; m <<= 1)
        #pragma unroll
        for (int r = 0; r < 4; ++r) rsq[r] += __shfl_xor(rsq[r], m);
    if (colid == 0) {
        #pragma unroll
        for (int r = 0; r < 4; ++r)
            sq2[(size_t)row0 + w * 16 + quad * 4 + r] = rsq[r];
    }
    __syncthreads();
    for (int id = t; id < 96 * 8; id += 256) {
        const int row = id >> 3, part = id & 7;
        *(short8*)&h2T[((size_t)b * 96 + row) * NN + n0 + part * 8] =
            *(const short8*)&Tbuf[row * 72 + part * 8];
    }
}

// ---------------------------------------------------------------------------
// Flash-attention graph conv, register-chained; weights/bias read from
// prepped global (padded) buffers in the epilogue only. LDS = K/V tiles + sq.
// ---------------------------------------------------------------------------
template<int C_PAD, int C_OUT, int JS, bool HAS_OUT, bool DO_MEAN>
__global__ __launch_bounds__(256) void attn_conv_kernel(
    const ushort* __restrict__ h, const ushort* __restrict__ hT,
    const float* __restrict__ sqg,
    const ushort* __restrict__ WtG, const float* __restrict__ biasP,
    ushort* __restrict__ ho, ushort* __restrict__ hoT, float* __restrict__ sqo,
    float* __restrict__ mean_out)
{
    constexpr int KF  = C_PAD / 32;
    constexpr int CS  = C_PAD / 16;
    constexpr int KST = C_PAD + 8;       // 208 B / 144 B rows: 16B-divisible
    constexpr int VST = 64 + 8;
    constexpr int NKLD = (64 * C_PAD / 8) / 256;
    constexpr int NVLD = (C_PAD * 8) / 256;

    __shared__ __attribute__((aligned(16))) ushort Krow[64 * KST];
    __shared__ __attribute__((aligned(16))) ushort Vcol[C_PAD * VST];
    __shared__ float sqs[64];

    const int t = threadIdx.x;
    const int lane = t & 63, w = t >> 6;
    const int colid = lane & 15, quad = lane >> 4;
    const int b = blockIdx.x >> 5;
    const int n0blk = (blockIdx.x & 31) * 64;

    const float LOG2E  = 1.44269504088896340736f;
    const float TWOL2E = 2.88539008177792681472f;

    // Q frags (x32 B-operand): lane holds Q[qrow=colid][k=quad*8+j]
    short8 qf[KF];
    {
        const ushort* qrow = h + (size_t)((size_t)b * NN + n0blk + w * 16 + colid) * C_PAD;
        #pragma unroll
        for (int kf = 0; kf < KF; ++kf)
            qf[kf] = *(const short8*)&qrow[kf * 32 + quad * 8];
    }
    const float sqnQL = sqg[(size_t)b * NN + n0blk + w * 16 + colid] * LOG2E;

    f32x4 o[CS];
    #pragma unroll
    for (int cs = 0; cs < CS; ++cs) o[cs] = (f32x4){0.f, 0.f, 0.f, 0.f};
    float rs = 0.f;

    // prefetch tile 0
    short8 kreg[NKLD], vreg[NVLD];
    float sqreg = 0.f;
    {
        const ushort* hsrc = h + (size_t)((size_t)b * NN) * C_PAD;
        #pragma unroll
        for (int i = 0; i < NKLD; ++i)
            kreg[i] = *(const short8*)&hsrc[(t + i * 256) * 8];
        #pragma unroll
        for (int i = 0; i < NVLD; ++i) {
            const int id = t + i * 256, c = id >> 3, pt = id & 7;
            vreg[i] = *(const short8*)&hT[((size_t)b * C_PAD + c) * NN + pt * 8];
        }
        if (t < 64) sqreg = sqg[(size_t)b * NN + t];
    }

    for (int n0 = 0; n0 < NN; n0 += 64) {
        if (n0) __syncthreads();
        #pragma unroll
        for (int i = 0; i < NKLD; ++i) {
            const int id = t + i * 256;
            const int row = id / (C_PAD / 8), pt = id % (C_PAD / 8);
            *(short8*)&Krow[row * KST + pt * 8] = kreg[i];
        }
        #pragma unroll
        for (int i = 0; i < NVLD; ++i) {
            const int id = t + i * 256, c = id >> 3, pt = id & 7;
            *(short8*)&Vcol[c * VST + pt * 8] = vreg[i];
        }
        if (t < 64) sqs[t] = sqreg;
        if (n0 + 64 < NN) {
            const int n1 = n0 + 64;
            const ushort* hsrc = h + (size_t)((size_t)b * NN + n1) * C_PAD;
            #pragma unroll
            for (int i = 0; i < NKLD; ++i)
                kreg[i] = *(const short8*)&hsrc[(t + i * 256) * 8];
            #pragma unroll
            for (int i = 0; i < NVLD; ++i) {
                const int id = t + i * 256, c = id >> 3, pt = id & 7;
                vreg[i] = *(const short8*)&hT[((size_t)b * C_PAD + c) * NN + n1 + pt * 8];
            }
            if (t < 64) sqreg = sqg[(size_t)b * NN + n1 + t];
        }
        __syncthreads();

        #pragma unroll
        for (int nc = 0; nc < 4; ++nc) {
            // S^T: A = K rows (key=nc*16+colid), B = Q
            f32x4 st = (f32x4){0.f, 0.f, 0.f, 0.f};
            #pragma unroll
            for (int cc = 0; cc < KF; ++cc) {
                const short8 kf_ = *(const short8*)&Krow[(nc * 16 + colid) * KST + cc * 32 + quad * 8];
                st = __builtin_amdgcn_mfma_f32_16x16x32_bf16(kf_, qf[cc], st, 0, 0, 0);
            }
            // p = exp2(2*s*log2e - sq_m*log2e - sq_n*log2e)
            const f32x4 smv = *(const f32x4*)&sqs[nc * 16 + quad * 4];
            float p[4];
            #pragma unroll
            for (int r = 0; r < 4; ++r) {
                p[r] = exp2f(fmaf(st[r], TWOL2E, fmaf(smv[r], -LOG2E, -sqnQL)));
                rs += p[r];
            }
            U2S pk_;
            pk_.u[0] = pkbf(p[1], p[0]);
            pk_.u[1] = pkbf(p[3], p[2]);
            const short4v pk = pk_.s;
            // O^T += V^T @ P^T  (x16; A = V^T rows)
            #pragma unroll
            for (int cs = 0; cs < CS; ++cs) {
                const short4v vf = *(const short4v*)&Vcol[(cs * 16 + colid) * VST + nc * 16 + quad * 4];
                o[cs] = __builtin_amdgcn_mfma_f32_16x16x16bf16_1k(vf, pk, o[cs], 0, 0, 0);
            }
        }
    }
    __syncthreads();                           // Krow free for reuse as Tbuf

    rs += __shfl_xor(rs, 16);
    rs += __shfl_xor(rs, 32);
    const float rinv = 1.f / rs;

    short4v oaf[CS];
    #pragma unroll
    for (int cs = 0; cs < CS; ++cs) {
        U2S o_;
        o_.u[0] = pkbf(o[cs][1] * rinv, o[cs][0] * rinv);
        o_.u[1] = pkbf(o[cs][3] * rinv, o[cs][2] * rinv);
        oaf[cs] = o_.s;
    }

    ushort* Tbuf = Krow;
    float rsq[4] = {0.f, 0.f, 0.f, 0.f};
    float msum = 0.f;

    #pragma unroll
    for (int js = 0; js < (HAS_OUT ? 4 : JS); ++js) {
        float v[4];
        if (js < JS) {
            f32x4 acc = (f32x4){0.f, 0.f, 0.f, 0.f};
            #pragma unroll
            for (int cs = 0; cs < CS; ++cs) {
                const short4v wf = *(const short4v*)&WtG[(js * 16 + colid) * C_PAD + cs * 16 + quad * 4];
                acc = __builtin_amdgcn_mfma_f32_16x16x16bf16_1k(oaf[cs], wf, acc, 0, 0, 0);
            }
            const float bj = biasP[js * 16 + colid];
            #pragma unroll
            for (int r = 0; r < 4; ++r) v[r] = fmaxf(acc[r] + bj, 0.f);
        } else {
            #pragma unroll
            for (int r = 0; r < 4; ++r) v[r] = 0.f;
        }
        if (HAS_OUT) {
            #pragma unroll
            for (int r = 0; r < 4; ++r) {
                const int grow = n0blk + w * 16 + quad * 4 + r;
                ho[(size_t)((size_t)b * NN + grow) * 64 + js * 16 + colid] = f2bf(v[r]);
                Tbuf[(js * 16 + colid) * 72 + w * 16 + quad * 4 + r] = f2bf(v[r]);
                rsq[r] += v[r] * v[r];
            }
        }
        if (DO_MEAN) {
            #pragma unroll
            for (int r = 0; r < 4; ++r) msum += v[r];
        }
    }

    if (HAS_OUT) {
        #pragma unroll
        for (int m = 1; m <= 8; m <<= 1)
            #pragma unroll
            for (int r = 0; r < 4; ++r) rsq[r] += __shfl_xor(rsq[r], m);
        if (colid == 0) {
            #pragma unroll
            for (int r = 0; r < 4; ++r)
                sqo[(size_t)b * NN + n0blk + w * 16 + quad * 4 + r] = rsq[r];
        }
        __syncthreads();
        for (int id = t; id < 64 * 8; id += 256) {
            const int row = id >> 3, part = id & 7;
            *(short8*)&hoT[((size_t)b * 64 + row) * NN + n0blk + part * 8] =
                *(const short8*)&Tbuf[row * 72 + part * 8];
        }
    }
    if (DO_MEAN) {
        msum += __shfl_xor(msum, 16);
        msum += __shfl_xor(msum, 32);
        if (lane < C_OUT) atomicAdd(&mean_out[b * C_OUT + lane], msum * (1.f / NN));
    }
}

// ---------------------------------------------------------------------------
// Final classifier + softmax over 2 logits.
// ---------------------------------------------------------------------------
__global__ __launch_bounds__(64) void final_kernel(
    const float* __restrict__ mean, const float* __restrict__ Wf,
    const float* __restrict__ bf, float* __restrict__ out)
{
    const int t = threadIdx.x;
    const int b = t >> 1, k = t & 1;
    float acc = bf[k];
    #pragma unroll
    for (int c = 0; c < H4; ++c) acc += mean[b * H4 + c] * Wf[c * 2 + k];
    const float other = __shfl_xor(acc, 1);
    const float mx = fmaxf(acc, other);
    const float e  = __expf(acc - mx);
    const float eo = __expf(other - mx);
    out[t] = e / (e + eo);
}

extern "C" void kernel_launch(void* const* d_in, const int* in_sizes, int n_in,
                              void* d_out, int out_size, void* d_ws, size_t ws_size,
                              hipStream_t stream) {
    const float* x   = (const float*)d_in[0];
    const float* W1  = (const float*)d_in[1];
    const float* b1  = (const float*)d_in[2];
    const float* W2  = (const float*)d_in[3];
    const float* b2  = (const float*)d_in[4];
    const float* Wg1 = (const float*)d_in[5];
    const float* bg1 = (const float*)d_in[6];
    const float* Wg2 = (const float*)d_in[7];
    const float* bg2 = (const float*)d_in[8];
    const float* Wf  = (const float*)d_in[9];
    const float* bf  = (const float*)d_in[10];

    ushort* h2   = (ushort*)d_ws;                        // [B*N][96] bf16
    ushort* h2T  = h2  + (size_t)BB * NN * 96;           // [B][96][N]
    float*  sq2  = (float*)(h2T + (size_t)BB * 96 * NN); // [B*N]
    ushort* h3   = (ushort*)(sq2 + (size_t)BB * NN);     // [B*N][64]
    ushort* h3T  = h3  + (size_t)BB * NN * 64;           // [B][64][N]
    float*  sq3  = (float*)(h3T + (size_t)BB * 64 * NN); // [B*N]
    float*  meanb = sq3 + (size_t)BB * NN;               // [B*5] (+pad to 160)
    ushort* Wt1  = (ushort*)(meanb + 160);               // [160][320]
    ushort* Wt2  = Wt1 + (size_t)H1 * D_IN;              // [80][160]
    ushort* Wg1T = Wt2 + (size_t)H2 * H1;                // [48][96]
    float*  bg1P = (float*)(Wg1T + 48 * 96);             // [48]
    ushort* Wg2T = (ushort*)(bg1P + 48);                 // [16][64]
    float*  bg2P = (float*)(Wg2T + 16 * 64);             // [16]

    hipMemsetAsync(meanb, 0, BB * H4 * sizeof(float), stream);

    prep_weights_kernel<<<64, 256, 0, stream>>>(W1, W2, Wg1, bg1, Wg2, bg2,
                                                Wt1, Wt2, Wg1T, bg1P, Wg2T, bg2P);
    mlp_mfma_kernel<<<BB * NN / 64, 256, 0, stream>>>(x, Wt1, b1, Wt2, b2, h2, h2T, sq2);
    attn_conv_kernel<96, 40, 3, true,  false><<<BB * NN / 64, 256, 0, stream>>>(
        h2, h2T, sq2, Wg1T, bg1P, h3, h3T, sq3, nullptr);
    attn_conv_kernel<64, 5, 1, false, true><<<BB * NN / 64, 256, 0, stream>>>(
        h3, h3T, sq3, Wg2T, bg2P, nullptr, nullptr, nullptr, meanb);
    final_kernel<<<1, 64, 0, stream>>>(meanb, Wf, bf, (float*)d_out);
}

// Round 7
// 332.562 us; speedup vs baseline: 1.1324x; 1.1324x over previous
//
#include <hip/hip_runtime.h>
#include <math.h>

#define BB 32
#define NN 2048
#define D_IN 320
#define H1 160
#define H2 80
#define H4 5

typedef __attribute__((ext_vector_type(8))) short short8;
typedef __attribute__((ext_vector_type(4))) short short4v;
typedef __attribute__((ext_vector_type(4))) float f32x4;
typedef __attribute__((ext_vector_type(16))) float f32x16;

__device__ inline ushort f2bf(float f) {
    union { float f; unsigned u; } v; v.f = f;
    unsigned r = v.u + 0x7fff + ((v.u >> 16) & 1);   // RNE
    return (ushort)(r >> 16);
}
__device__ inline float bf2f(ushort u) {
    union { float f; unsigned u; } v; v.u = ((unsigned)u) << 16;
    return v.f;
}
// pack 2 floats -> 2 bf16 in one dword (lo in low half): round-half-up + v_perm
__device__ inline unsigned pkbf(float hi, float lo) {
    union { float f; unsigned u; } a, b; a.f = hi; b.f = lo;
    return __builtin_amdgcn_perm(a.u + 0x8000u, b.u + 0x8000u, 0x07060302u);
}
union U2S { unsigned u[2]; short4v s; };
union U4S { unsigned u[4]; short8 s; };

// ---------------------------------------------------------------------------
// Prep: bf16-transpose weights. Wt1[160][320], Wt2[80][160],
// Wg1T[64][96] (+bg1P[64]), Wg2T[32][64] (+bg2P[32]) zero-padded.
// ---------------------------------------------------------------------------
__global__ __launch_bounds__(256) void prep_weights_kernel(
    const float* __restrict__ W1, const float* __restrict__ W2,
    const float* __restrict__ Wg1, const float* __restrict__ bg1,
    const float* __restrict__ Wg2, const float* __restrict__ bg2,
    ushort* __restrict__ Wt1, ushort* __restrict__ Wt2,
    ushort* __restrict__ Wg1T, float* __restrict__ bg1P,
    ushort* __restrict__ Wg2T, float* __restrict__ bg2P)
{
    const int id0 = blockIdx.x * 256 + threadIdx.x;
    const int stride = gridDim.x * 256;
    for (int i = id0; i < H1 * D_IN; i += stride) {
        const int j = i / D_IN, c = i % D_IN;
        Wt1[i] = f2bf(W1[c * H1 + j]);
    }
    for (int i = id0; i < H2 * H1; i += stride) {
        const int j = i / H1, c = i % H1;
        Wt2[i] = f2bf(W2[c * H2 + j]);
    }
    for (int i = id0; i < 64 * 96; i += stride) {
        const int j = i / 96, c = i % 96;
        Wg1T[i] = (j < 40 && c < 80) ? f2bf(Wg1[c * 40 + j]) : (ushort)0;
    }
    for (int i = id0; i < 32 * 64; i += stride) {
        const int j = i / 64, c = i % 64;
        Wg2T[i] = (j < 5 && c < 40) ? f2bf(Wg2[c * 5 + j]) : (ushort)0;
    }
    if (id0 < 64) bg1P[id0] = (id0 < 40) ? bg1[id0] : 0.f;
    if (id0 < 32) bg2P[id0] = (id0 < 5) ? bg2[id0] : 0.f;
}

// ---------------------------------------------------------------------------
// MFMA MLP (R5 structure: LDS-staged weights): h2 = relu(relu(x@W1+b1)@W2+b2).
// 64 rows/block, 256 thr / 4 waves. Emits bf16 h2 (pad 96), h2T, sq2.
// ---------------------------------------------------------------------------
__global__ __launch_bounds__(256) void mlp_mfma_kernel(
    const float* __restrict__ x,
    const ushort* __restrict__ Wt1, const float* __restrict__ b1,
    const ushort* __restrict__ Wt2, const float* __restrict__ b2,
    ushort* __restrict__ h2, ushort* __restrict__ h2T, float* __restrict__ sq2)
{
    constexpr int XST  = 72;
    constexpr int W1ST = 72;
    constexpr int W2ST = 168;
    constexpr int H1ST = 168;

    __shared__ __attribute__((aligned(16))) ushort h1t[64 * H1ST];  // aliases xs
    __shared__ __attribute__((aligned(16))) ushort ws1[H1 * W1ST];  // aliases Tbuf
    __shared__ __attribute__((aligned(16))) ushort ws2[H2 * W2ST];
    __shared__ float b1s[H1];
    __shared__ float b2s[H2];

    ushort* xs = h1t;

    const int t = threadIdx.x;
    const int lane = t & 63, w = t >> 6;
    const int colid = lane & 15, quad = lane >> 4;
    const int row0 = blockIdx.x * 64;
    const int b = row0 / NN, n0 = row0 % NN;

    if (t < H1) b1s[t] = b1[t];
    if (t < H2) b2s[t] = b2[t];

    for (int id = t; id < H2 * H1 / 8; id += 256) {
        const int j = id / 20, part = id % 20;
        *(short8*)&ws2[j * W2ST + part * 8] = *(const short8*)&Wt2[j * H1 + part * 8];
    }

    f32x4 c1[10];
    #pragma unroll
    for (int ns = 0; ns < 10; ++ns) c1[ns] = (f32x4){0.f, 0.f, 0.f, 0.f};

    float4 xr[4];
    short8 wr[5];
    {
        #pragma unroll
        for (int i = 0; i < 4; ++i) {
            const int id = t + i * 256, row = id >> 4, c4 = id & 15;
            xr[i] = *(const float4*)&x[(size_t)(row0 + row) * D_IN + c4 * 4];
        }
        #pragma unroll
        for (int i = 0; i < 5; ++i) {
            const int id = t + i * 256, j = id >> 3, part = id & 7;
            wr[i] = *(const short8*)&Wt1[j * D_IN + part * 8];
        }
    }

    for (int kc = 0; kc < 5; ++kc) {
        if (kc) __syncthreads();
        #pragma unroll
        for (int i = 0; i < 4; ++i) {
            const int id = t + i * 256, row = id >> 4, c4 = id & 15;
            uint2 up;
            up.x = pkbf(xr[i].y, xr[i].x);
            up.y = pkbf(xr[i].w, xr[i].z);
            *(uint2*)&xs[row * XST + c4 * 4] = up;
        }
        #pragma unroll
        for (int i = 0; i < 5; ++i) {
            const int id = t + i * 256, j = id >> 3, part = id & 7;
            *(short8*)&ws1[j * W1ST + part * 8] = wr[i];
        }
        if (kc < 4) {
            const int k0 = (kc + 1) * 64;
            #pragma unroll
            for (int i = 0; i < 4; ++i) {
                const int id = t + i * 256, row = id >> 4, c4 = id & 15;
                xr[i] = *(const float4*)&x[(size_t)(row0 + row) * D_IN + k0 + c4 * 4];
            }
            #pragma unroll
            for (int i = 0; i < 5; ++i) {
                const int id = t + i * 256, j = id >> 3, part = id & 7;
                wr[i] = *(const short8*)&Wt1[j * D_IN + k0 + part * 8];
            }
        }
        __syncthreads();

        short8 af[2];
        #pragma unroll
        for (int kf = 0; kf < 2; ++kf)
            af[kf] = *(const short8*)&xs[(w * 16 + colid) * XST + kf * 32 + quad * 8];
        #pragma unroll
        for (int ns = 0; ns < 10; ++ns) {
            #pragma unroll
            for (int kf = 0; kf < 2; ++kf) {
                const short8 bf = *(const short8*)&ws1[(ns * 16 + colid) * W1ST + kf * 32 + quad * 8];
                c1[ns] = __builtin_amdgcn_mfma_f32_16x16x32_bf16(af[kf], bf, c1[ns], 0, 0, 0);
            }
        }
    }
    __syncthreads();                            // xs dead -> h1t reuse

    #pragma unroll
    for (int ns = 0; ns < 10; ++ns) {
        const float bj = b1s[ns * 16 + colid];
        #pragma unroll
        for (int r = 0; r < 4; ++r)
            h1t[(w * 16 + quad * 4 + r) * H1ST + ns * 16 + colid] =
                f2bf(fmaxf(c1[ns][r] + bj, 0.f));
    }
    __asm__ volatile("s_waitcnt lgkmcnt(0)" ::: "memory");  // wave-private rows

    short8 a2[5];
    #pragma unroll
    for (int kf = 0; kf < 5; ++kf)
        a2[kf] = *(const short8*)&h1t[(w * 16 + colid) * H1ST + kf * 32 + quad * 8];

    f32x4 c2[5];
    #pragma unroll
    for (int js = 0; js < 5; ++js) {
        f32x4 acc = (f32x4){0.f, 0.f, 0.f, 0.f};
        #pragma unroll
        for (int kf = 0; kf < 5; ++kf) {
            const short8 wb = *(const short8*)&ws2[(js * 16 + colid) * W2ST + kf * 32 + quad * 8];
            acc = __builtin_amdgcn_mfma_f32_16x16x32_bf16(a2[kf], wb, acc, 0, 0, 0);
        }
        c2[js] = acc;
    }
    __syncthreads();                            // ws1 dead -> Tbuf reuse

    ushort* Tbuf = ws1;                         // [96][72]
    float rsq[4] = {0.f, 0.f, 0.f, 0.f};
    #pragma unroll
    for (int js = 0; js < 5; ++js) {
        const float bj = b2s[js * 16 + colid];
        #pragma unroll
        for (int r = 0; r < 4; ++r) {
            const ushort u = f2bf(fmaxf(c2[js][r] + bj, 0.f));
            const float vv = bf2f(u);
            rsq[r] += vv * vv;
            h2[(size_t)(row0 + w * 16 + quad * 4 + r) * 96 + js * 16 + colid] = u;
            Tbuf[(js * 16 + colid) * 72 + w * 16 + quad * 4 + r] = u;
        }
    }
    {
        const short8 z8 = {0, 0, 0, 0, 0, 0, 0, 0};
        if (t < 128) {
            const int row = t >> 1, part = t & 1;
            *(short8*)&h2[(size_t)(row0 + row) * 96 + 80 + part * 8] = z8;
        }
        if (t < 128) {
            const int row = 80 + (t >> 3), part = t & 7;
            *(short8*)&Tbuf[row * 72 + part * 8] = z8;
        }
    }
    #pragma unroll
    for (int m = 1; m <= 8; m <<= 1)
        #pragma unroll
        for (int r = 0; r < 4; ++r) rsq[r] += __shfl_xor(rsq[r], m);
    if (colid == 0) {
        #pragma unroll
        for (int r = 0; r < 4; ++r)
            sq2[(size_t)row0 + w * 16 + quad * 4 + r] = rsq[r];
    }
    __syncthreads();
    for (int id = t; id < 96 * 8; id += 256) {
        const int row = id >> 3, part = id & 7;
        *(short8*)&h2T[((size_t)b * 96 + row) * NN + n0 + part * 8] =
            *(const short8*)&Tbuf[row * 72 + part * 8];
    }
}

// ---------------------------------------------------------------------------
// Flash-attention graph conv on 32x32x16 bf16 MFMA. 4 waves x 32 q-rows =
// 128 rows/block. Key-permutation phi(k) = (k&3)+8*((k&7)>>2)+4*(k>>3)
// applied consistently to PV's V-operand and to the projection's W-operand,
// so S's C-layout feeds MFMA B-operands directly (no LDS round trips).
// ---------------------------------------------------------------------------
template<int C_PAD, int C_OUT, int JT, bool HAS_OUT, bool DO_MEAN>
__global__ __launch_bounds__(256) void attn_conv_kernel(
    const ushort* __restrict__ h, const ushort* __restrict__ hT,
    const float* __restrict__ sqg,
    const ushort* __restrict__ WtG, const float* __restrict__ biasP,
    ushort* __restrict__ ho, ushort* __restrict__ hoT, float* __restrict__ sqo,
    float* __restrict__ mean_out)
{
    constexpr int CF  = C_PAD / 16;      // 16-ch chunks (6 / 4)
    constexpr int CSV = C_PAD / 32;      // 32-ch tiles  (3 / 2)
    constexpr int KST = C_PAD + 8;
    constexpr int VST = 64 + 8;
    constexpr int NKLD = (64 * C_PAD / 8) / 256;
    constexpr int NVLD = (C_PAD * 8) / 256;
    constexpr int TST  = 136;            // Tbuf stride (128 qcols + 8)
    constexpr int LDSN = 64 * KST + C_PAD * VST;

    __shared__ __attribute__((aligned(16))) ushort ldsbuf[LDSN];
    __shared__ __attribute__((aligned(16))) float sqs[64];
    ushort* Krow = ldsbuf;
    ushort* Vcol = ldsbuf + 64 * KST;

    const int t = threadIdx.x;
    const int lane = t & 63, w = t >> 6;
    const int m32 = lane & 31, hl = lane >> 5;
    const int b = blockIdx.x >> 4;             // NN/128 = 16 row-tiles/batch
    const int n0blk = (blockIdx.x & 15) * 128;
    const int qrow = n0blk + w * 32 + m32;

    const float LOG2E  = 1.44269504088896340736f;
    const float TWOL2E = 2.88539008177792681472f;

    // Q B-operand frags: lane holds Q[qrow=m32][ch = 16c + 8*hl + j]
    short8 qf[CF];
    {
        const ushort* qr = h + ((size_t)b * NN + qrow) * C_PAD;
        #pragma unroll
        for (int c = 0; c < CF; ++c)
            qf[c] = *(const short8*)&qr[c * 16 + hl * 8];
    }
    const float sqnQL = sqg[(size_t)b * NN + qrow] * LOG2E;

    f32x16 o[CSV];
    #pragma unroll
    for (int cs = 0; cs < CSV; ++cs)
        #pragma unroll
        for (int r = 0; r < 16; ++r) o[cs][r] = 0.f;
    float rs = 0.f;

    // prefetch tile 0
    short8 kreg[NKLD], vreg[NVLD];
    float sqreg = 0.f;
    {
        const ushort* hsrc = h + (size_t)((size_t)b * NN) * C_PAD;
        #pragma unroll
        for (int i = 0; i < NKLD; ++i)
            kreg[i] = *(const short8*)&hsrc[(t + i * 256) * 8];
        #pragma unroll
        for (int i = 0; i < NVLD; ++i) {
            const int id = t + i * 256, c = id >> 3, pt = id & 7;
            vreg[i] = *(const short8*)&hT[((size_t)b * C_PAD + c) * NN + pt * 8];
        }
        if (t < 64) sqreg = sqg[(size_t)b * NN + t];
    }

    for (int n0 = 0; n0 < NN; n0 += 64) {
        if (n0) __syncthreads();               // prev readers done
        #pragma unroll
        for (int i = 0; i < NKLD; ++i) {
            const int id = t + i * 256;
            const int row = id / (C_PAD / 8), pt = id % (C_PAD / 8);
            *(short8*)&Krow[row * KST + pt * 8] = kreg[i];
        }
        #pragma unroll
        for (int i = 0; i < NVLD; ++i) {
            const int id = t + i * 256, c = id >> 3, pt = id & 7;
            *(short8*)&Vcol[c * VST + pt * 8] = vreg[i];
        }
        if (t < 64) sqs[t] = sqreg;
        if (n0 + 64 < NN) {
            const int n1 = n0 + 64;
            const ushort* hsrc = h + (size_t)((size_t)b * NN + n1) * C_PAD;
            #pragma unroll
            for (int i = 0; i < NKLD; ++i)
                kreg[i] = *(const short8*)&hsrc[(t + i * 256) * 8];
            #pragma unroll
            for (int i = 0; i < NVLD; ++i) {
                const int id = t + i * 256, c = id >> 3, pt = id & 7;
                vreg[i] = *(const short8*)&hT[((size_t)b * C_PAD + c) * NN + n1 + pt * 8];
            }
            if (t < 64) sqreg = sqg[(size_t)b * NN + n1 + t];
        }
        __syncthreads();                       // tile visible

        // two 32-key tiles per iteration
        #pragma unroll
        for (int T = 0; T < 2; ++T) {
            // S^T: A = K rows (key = 32T + m32), B = Q
            f32x16 st;
            #pragma unroll
            for (int r = 0; r < 16; ++r) st[r] = 0.f;
            #pragma unroll
            for (int c = 0; c < CF; ++c) {
                const short8 af = *(const short8*)&Krow[(T * 32 + m32) * KST + c * 16 + hl * 8];
                st = __builtin_amdgcn_mfma_f32_32x32x16_bf16(af, qf[c], st, 0, 0, 0);
            }
            // reg r: physical key = 32T + (r&3) + 8*(r>>2) + 4*hl
            float p[16];
            #pragma unroll
            for (int g = 0; g < 4; ++g) {
                const f32x4 smv = *(const f32x4*)&sqs[T * 32 + g * 8 + hl * 4];
                #pragma unroll
                for (int r2 = 0; r2 < 4; ++r2) {
                    const float pv = exp2f(fmaf(st[g * 4 + r2], TWOL2E,
                                                fmaf(smv[r2], -LOG2E, -sqnQL)));
                    p[g * 4 + r2] = pv;
                    rs += pv;
                }
            }
            // PV over two 16-key chunks; P C-regs ARE the B-operand (perm phi)
            #pragma unroll
            for (int c = 0; c < 2; ++c) {
                U4S pk_;
                #pragma unroll
                for (int bq = 0; bq < 4; ++bq)
                    pk_.u[bq] = pkbf(p[c * 8 + bq * 2 + 1], p[c * 8 + bq * 2]);
                const int kb = (T * 2 + c) * 16 + hl * 4;  // phi on V side
                #pragma unroll
                for (int cs = 0; cs < CSV; ++cs) {
                    U4S va;
                    *(short4v*)&va.u[0] = *(const short4v*)&Vcol[(cs * 32 + m32) * VST + kb];
                    *(short4v*)&va.u[2] = *(const short4v*)&Vcol[(cs * 32 + m32) * VST + kb + 8];
                    o[cs] = __builtin_amdgcn_mfma_f32_32x32x16_bf16(va.s, pk_.s, o[cs], 0, 0, 0);
                }
            }
        }
    }
    __syncthreads();                           // LDS free -> Tbuf reuse

    // denominator for this lane's qrow: sum the two hl key-classes
    rs += __shfl_xor(rs, 32);
    const float rinv = 1.f / rs;

    // O^T C-layout -> projection B-operand frags (same phi pattern, in-register)
    short8 ob[CF];
    #pragma unroll
    for (int cs = 0; cs < CSV; ++cs)
        #pragma unroll
        for (int c2 = 0; c2 < 2; ++c2) {
            U4S ob_;
            #pragma unroll
            for (int bq = 0; bq < 4; ++bq)
                ob_.u[bq] = pkbf(o[cs][c2 * 8 + bq * 2 + 1] * rinv,
                                 o[cs][c2 * 8 + bq * 2] * rinv);
            ob[cs * 2 + c2] = ob_.s;
        }

    ushort* Tbuf = ldsbuf;                     // [64][TST]
    float rsq = 0.f;
    float msum[4] = {0.f, 0.f, 0.f, 0.f};

    #pragma unroll
    for (int jt = 0; jt < JT; ++jt) {
        f32x16 acc;
        #pragma unroll
        for (int r = 0; r < 16; ++r) acc[r] = 0.f;
        #pragma unroll
        for (int cc = 0; cc < CF; ++cc) {
            const ushort* wrow = WtG + (size_t)(jt * 32 + m32) * C_PAD + cc * 16 + hl * 4;
            U4S wa;
            *(short4v*)&wa.u[0] = *(const short4v*)&wrow[0];
            *(short4v*)&wa.u[2] = *(const short4v*)&wrow[8];
            acc = __builtin_amdgcn_mfma_f32_32x32x16_bf16(wa.s, ob[cc], acc, 0, 0, 0);
        }
        // reg r: j' = jt*32 + (r&3) + 8*(r>>2) + 4*hl ; col = qrow = m32
        #pragma unroll
        for (int g = 0; g < 4; ++g) {
            const f32x4 bv = *(const f32x4*)&biasP[jt * 32 + g * 8 + hl * 4];
            float v[4];
            #pragma unroll
            for (int r2 = 0; r2 < 4; ++r2) {
                v[r2] = fmaxf(acc[g * 4 + r2] + bv[r2], 0.f);
                rsq += v[r2] * v[r2];
            }
            if (HAS_OUT) {
                U2S uo;
                uo.u[0] = pkbf(v[1], v[0]);
                uo.u[1] = pkbf(v[3], v[2]);
                const int jb = jt * 32 + g * 8 + hl * 4;
                *(short4v*)&ho[((size_t)b * NN + qrow) * 64 + jb] = uo.s;
                const int qc = w * 32 + m32;
                #pragma unroll
                for (int r2 = 0; r2 < 4; ++r2)
                    Tbuf[(jb + r2) * TST + qc] =
                        (ushort)(uo.u[r2 >> 1] >> ((r2 & 1) * 16));
            }
            if (DO_MEAN && jt == 0 && g == 0) {
                #pragma unroll
                for (int r2 = 0; r2 < 4; ++r2) msum[r2] = v[r2];
            }
        }
    }

    if (HAS_OUT) {
        const float rsq2 = rsq + __shfl_xor(rsq, 32);
        if (hl == 0) sqo[(size_t)b * NN + qrow] = rsq2;
        __syncthreads();
        // coalesced transposed store: hoT[b][j'][n0blk..+128]
        for (int id = t; id < 64 * 16; id += 256) {
            const int row = id >> 4, part = id & 15;
            *(short8*)&hoT[((size_t)b * 64 + row) * NN + n0blk + part * 8] =
                *(const short8*)&Tbuf[row * TST + part * 8];
        }
    }
    if (DO_MEAN) {
        // sum over the wave's 32 qrows (j' padded cols are exactly zero)
        #pragma unroll
        for (int s = 1; s <= 16; s <<= 1)
            #pragma unroll
            for (int r2 = 0; r2 < 4; ++r2) msum[r2] += __shfl_xor(msum[r2], s);
        if (m32 == 0) {
            if (hl == 0) {
                #pragma unroll
                for (int r2 = 0; r2 < 4; ++r2)
                    atomicAdd(&mean_out[b * C_OUT + r2], msum[r2] * (1.f / NN));
            } else {
                atomicAdd(&mean_out[b * C_OUT + 4], msum[0] * (1.f / NN));
            }
        }
    }
}

// ---------------------------------------------------------------------------
// Final classifier + softmax over 2 logits.
// ---------------------------------------------------------------------------
__global__ __launch_bounds__(64) void final_kernel(
    const float* __restrict__ mean, const float* __restrict__ Wf,
    const float* __restrict__ bf, float* __restrict__ out)
{
    const int t = threadIdx.x;
    const int b = t >> 1, k = t & 1;
    float acc = bf[k];
    #pragma unroll
    for (int c = 0; c < H4; ++c) acc += mean[b * H4 + c] * Wf[c * 2 + k];
    const float other = __shfl_xor(acc, 1);
    const float mx = fmaxf(acc, other);
    const float e  = __expf(acc - mx);
    const float eo = __expf(other - mx);
    out[t] = e / (e + eo);
}

extern "C" void kernel_launch(void* const* d_in, const int* in_sizes, int n_in,
                              void* d_out, int out_size, void* d_ws, size_t ws_size,
                              hipStream_t stream) {
    const float* x   = (const float*)d_in[0];
    const float* W1  = (const float*)d_in[1];
    const float* b1  = (const float*)d_in[2];
    const float* W2  = (const float*)d_in[3];
    const float* b2  = (const float*)d_in[4];
    const float* Wg1 = (const float*)d_in[5];
    const float* bg1 = (const float*)d_in[6];
    const float* Wg2 = (const float*)d_in[7];
    const float* bg2 = (const float*)d_in[8];
    const float* Wf  = (const float*)d_in[9];
    const float* bf  = (const float*)d_in[10];

    ushort* h2   = (ushort*)d_ws;                        // [B*N][96] bf16
    ushort* h2T  = h2  + (size_t)BB * NN * 96;           // [B][96][N]
    float*  sq2  = (float*)(h2T + (size_t)BB * 96 * NN); // [B*N]
    ushort* h3   = (ushort*)(sq2 + (size_t)BB * NN);     // [B*N][64]
    ushort* h3T  = h3  + (size_t)BB * NN * 64;           // [B][64][N]
    float*  sq3  = (float*)(h3T + (size_t)BB * 64 * NN); // [B*N]
    float*  meanb = sq3 + (size_t)BB * NN;               // [B*5] (+pad to 160)
    ushort* Wt1  = (ushort*)(meanb + 160);               // [160][320]
    ushort* Wt2  = Wt1 + (size_t)H1 * D_IN;              // [80][160]
    ushort* Wg1T = Wt2 + (size_t)H2 * H1;                // [64][96]
    float*  bg1P = (float*)(Wg1T + 64 * 96);             // [64]
    ushort* Wg2T = (ushort*)(bg1P + 64);                 // [32][64]
    float*  bg2P = (float*)(Wg2T + 32 * 64);             // [32]

    hipMemsetAsync(meanb, 0, BB * H4 * sizeof(float), stream);

    prep_weights_kernel<<<64, 256, 0, stream>>>(W1, W2, Wg1, bg1, Wg2, bg2,
                                                Wt1, Wt2, Wg1T, bg1P, Wg2T, bg2P);
    mlp_mfma_kernel<<<BB * NN / 64, 256, 0, stream>>>(x, Wt1, b1, Wt2, b2, h2, h2T, sq2);
    attn_conv_kernel<96, 40, 2, true,  false><<<BB * NN / 128, 256, 0, stream>>>(
        h2, h2T, sq2, Wg1T, bg1P, h3, h3T, sq3, nullptr);
    attn_conv_kernel<64, 5, 1, false, true><<<BB * NN / 128, 256, 0, stream>>>(
        h3, h3T, sq3, Wg2T, bg2P, nullptr, nullptr, nullptr, meanb);
    final_kernel<<<1, 64, 0, stream>>>(meanb, Wf, bf, (float*)d_out);
}